// Round 1
// baseline (49.191 us; speedup 1.0000x reference)
//
#include <hip/hip_runtime.h>

namespace {
constexpr int Bn = 64;
constexpr int Ln = 512;
constexpr int Hn = 768;
constexpr int Dn = 16;
constexpr int Sn = 64;
constexpr int Qn = 32;
constexpr float NEGV = -900000.0f;
}

// ---------------------------------------------------------------------------
// Kernel 1: per-position scores for both heads in one pass over hidden_states.
//   sdoc[b*L + l] = hidden[b,l,:] . W_doc + b_doc
//   sq  [b*L + l] = hidden[b,l,:] . W_query + b_query
// 256 threads = 4 waves; each wave handles one row per iteration.
// ---------------------------------------------------------------------------
__global__ __launch_bounds__(256) void k_scores(
    const float* __restrict__ hs,
    const float* __restrict__ Wd, const float* __restrict__ bd,
    const float* __restrict__ Wq, const float* __restrict__ bq,
    float* __restrict__ sdoc, float* __restrict__ sq)
{
    __shared__ float wd_sh[Hn];
    __shared__ float wq_sh[Hn];
    for (int i = threadIdx.x; i < Hn; i += 256) {
        wd_sh[i] = Wd[i];
        wq_sh[i] = Wq[i];
    }
    __syncthreads();

    const float bdv = bd[0];
    const float bqv = bq[0];
    const int wave = threadIdx.x >> 6;
    const int lane = threadIdx.x & 63;
    const int nrows = Bn * Ln;

    for (int row = blockIdx.x * 4 + wave; row < nrows; row += gridDim.x * 4) {
        const float* r = hs + (size_t)row * Hn;
        float ad = 0.f, aq = 0.f;
#pragma unroll
        for (int j = 0; j < 3; ++j) {
            const int e = (lane + 64 * j) * 4;               // 768 = 64 lanes * 3 * float4
            const float4 v = *reinterpret_cast<const float4*>(r + e);
            ad += v.x * wd_sh[e]     + v.y * wd_sh[e + 1]
                + v.z * wd_sh[e + 2] + v.w * wd_sh[e + 3];
            aq += v.x * wq_sh[e]     + v.y * wq_sh[e + 1]
                + v.z * wq_sh[e + 2] + v.w * wq_sh[e + 3];
        }
#pragma unroll
        for (int off = 32; off; off >>= 1) {
            ad += __shfl_down(ad, off);
            aq += __shfl_down(aq, off);
        }
        if (lane == 0) {
            sdoc[row] = ad + bdv;
            sq[row]   = aq + bqv;
        }
    }
}

// ---------------------------------------------------------------------------
// Kernel 2: doc pooling. One block per (b,d); 256 threads own 3 H-columns each.
// ---------------------------------------------------------------------------
__global__ __launch_bounds__(256) void k_doc(
    const float* __restrict__ hs, const float* __restrict__ sdoc,
    const int* __restrict__ qlen, const int* __restrict__ slens,
    float* __restrict__ out)
{
    const int b = blockIdx.x / Dn;
    const int d = blockIdx.x % Dn;

    __shared__ float alpha_sh[Sn];
    __shared__ int   idx_sh[Sn];
    __shared__ int   off_sh;

    if (threadIdx.x == 0) {
        int off = qlen[b] + 2;                 // offsets = qlen + 2 + exclusive-prefix(seq_lens)
        for (int j = 0; j < d; ++j) off += slens[b * Dn + j];
        off_sh = off;
    }
    __syncthreads();

    const int sl = slens[b * Dn + d];
    const int t = threadIdx.x;

    if (t < Sn) {                              // first wave: masked softmax over S=64
        int idx = off_sh + t;
        if (idx > Ln - 1) idx = Ln - 1;        // jnp.clip upper bound (lower is never hit)
        idx_sh[t] = idx;
        const float raw = (t < sl) ? sdoc[b * Ln + idx] : NEGV;
        float m = raw;
#pragma unroll
        for (int off = 32; off; off >>= 1) m = fmaxf(m, __shfl_xor(m, off));
        const float e = expf(raw - m);
        float den = e;
#pragma unroll
        for (int off = 32; off; off >>= 1) den += __shfl_xor(den, off);
        // masked positions multiply zeroed rows in the reference -> exact 0 contribution
        alpha_sh[t] = (t < sl) ? (e / den) : 0.f;
    }
    __syncthreads();

    float acc0 = 0.f, acc1 = 0.f, acc2 = 0.f;
    for (int s = 0; s < Sn; ++s) {
        const float a = alpha_sh[s];
        if (a > 0.f) {                         // wave-uniform branch; skips masked + underflowed
            const float* row = hs + (size_t)(b * Ln + idx_sh[s]) * Hn;
            acc0 += a * row[t];
            acc1 += a * row[t + 256];
            acc2 += a * row[t + 512];
        }
    }
    float* o = out + (size_t)(b * Dn + d) * Hn;
    o[t]       = acc0;
    o[t + 256] = acc1;
    o[t + 512] = acc2;
}

// ---------------------------------------------------------------------------
// Kernel 3: query pooling + broadcast to all D doc slots. One block per b.
// ---------------------------------------------------------------------------
__global__ __launch_bounds__(256) void k_query(
    const float* __restrict__ hs, const float* __restrict__ sq,
    const int* __restrict__ qlen, float* __restrict__ out2)
{
    const int b = blockIdx.x;
    const int t = threadIdx.x;
    const int ql = qlen[b];

    __shared__ float aq_sh[Qn];

    if (t < Qn) {                              // lanes 0..31: masked softmax over Q=32
        const float raw = (t < ql) ? sq[b * Ln + 1 + t] : NEGV;
        float m = raw;
#pragma unroll
        for (int off = 16; off; off >>= 1) m = fmaxf(m, __shfl_xor(m, off, 32));
        const float e = expf(raw - m);
        float den = e;
#pragma unroll
        for (int off = 16; off; off >>= 1) den += __shfl_xor(den, off, 32);
        aq_sh[t] = (t < ql) ? (e / den) : 0.f;
    }
    __syncthreads();

    float acc0 = 0.f, acc1 = 0.f, acc2 = 0.f;
    for (int q = 0; q < Qn; ++q) {
        const float a = aq_sh[q];
        if (a > 0.f) {
            const float* row = hs + (size_t)(b * Ln + 1 + q) * Hn;
            acc0 += a * row[t];
            acc1 += a * row[t + 256];
            acc2 += a * row[t + 512];
        }
    }
    for (int dd = 0; dd < Dn; ++dd) {
        float* o = out2 + (size_t)(b * Dn + dd) * Hn;
        o[t]       = acc0;
        o[t + 256] = acc1;
        o[t + 512] = acc2;
    }
}

extern "C" void kernel_launch(void* const* d_in, const int* in_sizes, int n_in,
                              void* d_out, int out_size, void* d_ws, size_t ws_size,
                              hipStream_t stream)
{
    const float* hs    = (const float*)d_in[0];   // (B,L,H) f32
    const float* Wd    = (const float*)d_in[1];   // (H,1)
    const float* bd    = (const float*)d_in[2];   // (1,)
    const float* Wq    = (const float*)d_in[3];   // (H,1)
    const float* bq    = (const float*)d_in[4];   // (1,)
    const int*   qlen  = (const int*)d_in[5];     // (B,)
    const int*   slens = (const int*)d_in[6];     // (B,D)

    float* out_doc = (float*)d_out;                       // (B,D,H) doc_pooled
    float* out_q   = out_doc + (size_t)Bn * Dn * Hn;      // (B,D,H) q_bcast

    float* sdoc = (float*)d_ws;                           // (B*L)
    float* sq   = sdoc + (size_t)Bn * Ln;                 // (B*L)

    k_scores<<<2048, 256, 0, stream>>>(hs, Wd, bd, Wq, bq, sdoc, sq);
    k_doc<<<Bn * Dn, 256, 0, stream>>>(hs, sdoc, qlen, slens, out_doc);
    k_query<<<Bn, 256, 0, stream>>>(hs, sq, qlen, out_q);
}

// Round 2
// 19.469 us; speedup vs baseline: 2.5266x; 2.5266x over previous
//
#include <hip/hip_runtime.h>

namespace {
constexpr int Bn = 64;
constexpr int Ln = 512;
constexpr int Hn = 768;
constexpr int Dn = 16;
constexpr int Sn = 64;
constexpr int Qn = 32;
constexpr float NEGV = -900000.0f;
}

// ---------------------------------------------------------------------------
// Single fused kernel.
//   blocks [0, Bn)            : query pooling for batch b = bid  (put first —
//                               they carry the 16x broadcast writes)
//   blocks [Bn, Bn + Bn*Dn)   : doc pooling for (b,d)
// Each block: phase 1 computes the per-row scores inline (rows are about to be
// read for pooling anyway — the score dot is nearly free), softmax in one
// wave, phase 2 re-reads rows (L1/L2 hot) for the weighted pool.
// Masked rows (s >= seq_len / q >= query_len) are never touched: in the
// reference they are zeroed AND get alpha=softmax(NEG)->~0, so their
// contribution is exactly 0.
// ---------------------------------------------------------------------------
__global__ __launch_bounds__(256) void k_fused(
    const float* __restrict__ hs,
    const float* __restrict__ Wd, const float* __restrict__ bd,
    const float* __restrict__ Wq, const float* __restrict__ bq,
    const int* __restrict__ qlen, const int* __restrict__ slens,
    float* __restrict__ out_doc, float* __restrict__ out_q)
{
    __shared__ float w_sh[Hn];
    __shared__ float alpha_sh[Sn];
    __shared__ int   base_sh;

    const int t = threadIdx.x;
    const int wave = t >> 6;
    const int lane = t & 63;
    const int bid = blockIdx.x;

    if (bid < Bn) {
        // ------------------------- query block -------------------------
        const int b = bid;
        const int ql = qlen[b];
        for (int i = t; i < Hn; i += 256) w_sh[i] = Wq[i];
        __syncthreads();

        // phase 1: scores for rows 1..ql (4 waves, one row per wave-iter)
        const float bqv = bq[0];
        for (int s = wave; s < ql; s += 4) {
            const float* r = hs + (size_t)(b * Ln + 1 + s) * Hn;
            float a = 0.f;
#pragma unroll
            for (int j = 0; j < 3; ++j) {
                const int e = (lane + 64 * j) * 4;
                const float4 v = *reinterpret_cast<const float4*>(r + e);
                a += v.x * w_sh[e] + v.y * w_sh[e + 1]
                   + v.z * w_sh[e + 2] + v.w * w_sh[e + 3];
            }
#pragma unroll
            for (int off = 32; off; off >>= 1) a += __shfl_down(a, off);
            if (lane == 0) alpha_sh[s] = a + bqv;
        }
        __syncthreads();

        // softmax over Q=32 in lanes 0..31 of wave 0
        if (t < Qn) {
            const float raw = (t < ql) ? alpha_sh[t] : NEGV;
            float m = raw;
#pragma unroll
            for (int off = 16; off; off >>= 1) m = fmaxf(m, __shfl_xor(m, off, 32));
            const float e = expf(raw - m);
            float den = e;
#pragma unroll
            for (int off = 16; off; off >>= 1) den += __shfl_xor(den, off, 32);
            alpha_sh[t] = (t < ql) ? (e / den) : 0.f;
        }
        __syncthreads();

        // phase 2: weighted pool over ql rows (rows are L1/L2 hot)
        float acc0 = 0.f, acc1 = 0.f, acc2 = 0.f;
#pragma unroll 2
        for (int s = 0; s < ql; ++s) {
            const float a = alpha_sh[s];
            const float* row = hs + (size_t)(b * Ln + 1 + s) * Hn;
            acc0 += a * row[t];
            acc1 += a * row[t + 256];
            acc2 += a * row[t + 512];
        }
        // broadcast to all D doc slots
        for (int dd = 0; dd < Dn; ++dd) {
            float* o = out_q + (size_t)(b * Dn + dd) * Hn;
            o[t]       = acc0;
            o[t + 256] = acc1;
            o[t + 512] = acc2;
        }
    } else {
        // -------------------------- doc block --------------------------
        const int id = bid - Bn;
        const int b = id >> 4;
        const int d = id & 15;
        for (int i = t; i < Hn; i += 256) w_sh[i] = Wd[i];
        if (t == 0) {
            int off = qlen[b] + 2;             // exclusive prefix of seq_lens
            for (int j = 0; j < d; ++j) off += slens[b * Dn + j];
            base_sh = off;
        }
        __syncthreads();

        const int sl = slens[b * Dn + d];      // 0..28 (< Sn); 0 => all-masked
        const int base = base_sh;
        const float bdv = bd[0];

        // phase 1: scores for rows 0..sl-1
        for (int s = wave; s < sl; s += 4) {
            int idx = base + s;
            if (idx > Ln - 1) idx = Ln - 1;
            const float* r = hs + (size_t)(b * Ln + idx) * Hn;
            float a = 0.f;
#pragma unroll
            for (int j = 0; j < 3; ++j) {
                const int e = (lane + 64 * j) * 4;
                const float4 v = *reinterpret_cast<const float4*>(r + e);
                a += v.x * w_sh[e] + v.y * w_sh[e + 1]
                   + v.z * w_sh[e + 2] + v.w * w_sh[e + 3];
            }
#pragma unroll
            for (int off = 32; off; off >>= 1) a += __shfl_down(a, off);
            if (lane == 0) alpha_sh[s] = a + bdv;
        }
        __syncthreads();

        // softmax over S=64 in wave 0 (sl==0 -> all alpha 0, output zeros)
        if (t < Sn) {
            const float raw = (t < sl) ? alpha_sh[t] : NEGV;
            float m = raw;
#pragma unroll
            for (int off = 32; off; off >>= 1) m = fmaxf(m, __shfl_xor(m, off));
            const float e = expf(raw - m);
            float den = e;
#pragma unroll
            for (int off = 32; off; off >>= 1) den += __shfl_xor(den, off);
            alpha_sh[t] = (t < sl) ? (e / den) : 0.f;
        }
        __syncthreads();

        // phase 2: weighted pool over sl rows
        float acc0 = 0.f, acc1 = 0.f, acc2 = 0.f;
#pragma unroll 2
        for (int s = 0; s < sl; ++s) {
            const float a = alpha_sh[s];
            int idx = base + s;
            if (idx > Ln - 1) idx = Ln - 1;
            const float* row = hs + (size_t)(b * Ln + idx) * Hn;
            acc0 += a * row[t];
            acc1 += a * row[t + 256];
            acc2 += a * row[t + 512];
        }
        float* o = out_doc + (size_t)(b * Dn + d) * Hn;
        o[t]       = acc0;
        o[t + 256] = acc1;
        o[t + 512] = acc2;
    }
}

extern "C" void kernel_launch(void* const* d_in, const int* in_sizes, int n_in,
                              void* d_out, int out_size, void* d_ws, size_t ws_size,
                              hipStream_t stream)
{
    const float* hs    = (const float*)d_in[0];   // (B,L,H) f32
    const float* Wd    = (const float*)d_in[1];   // (H,1)
    const float* bd    = (const float*)d_in[2];   // (1,)
    const float* Wq    = (const float*)d_in[3];   // (H,1)
    const float* bq    = (const float*)d_in[4];   // (1,)
    const int*   qlen  = (const int*)d_in[5];     // (B,)
    const int*   slens = (const int*)d_in[6];     // (B,D)

    float* out_doc = (float*)d_out;                       // (B,D,H) doc_pooled
    float* out_q   = out_doc + (size_t)Bn * Dn * Hn;      // (B,D,H) q_bcast

    k_fused<<<Bn + Bn * Dn, 256, 0, stream>>>(hs, Wd, bd, Wq, bq,
                                              qlen, slens, out_doc, out_q);
}